// Round 12
// baseline (4047.479 us; speedup 1.0000x reference)
//
#include <hip/hip_runtime.h>

#define S_ 2048
#define B_ 64
#define D_ 512
#define H_ 512
#define BH_ (B_*H_)
#define NMEM 8

typedef __attribute__((ext_vector_type(4))) float fx4;
typedef __attribute__((ext_vector_type(8))) short sx8;
typedef __attribute__((ext_vector_type(4))) unsigned int ux4;
typedef __attribute__((ext_vector_type(2))) unsigned int ux2;

__device__ __forceinline__ unsigned short f2bf(float f) {
    union { float f; unsigned int u; } v; v.f = f;
    return (unsigned short)((v.u + 0x7fffu + ((v.u >> 16) & 1u)) >> 16);
}
__device__ __forceinline__ float bf2f(unsigned short b) {
    union { float f; unsigned int u; } v; v.u = ((unsigned int)b) << 16;
    return v.f;
}
__device__ __forceinline__ unsigned int cvtpk(float a, float b) {
    unsigned int r;
    asm("v_cvt_pk_bf16_f32 %0, %1, %2" : "=v"(r) : "v"(a), "v"(b));
    return r;
}

// raw barrier WITHOUT vmcnt drain: LDS ops ordered, global loads/stores stay in flight
#define BAR() asm volatile("s_waitcnt lgkmcnt(0)\n\ts_barrier" ::: "memory")

// ---------------------------------------------------------------------------
// Phase 1: input projections (unchanged). xr/xz -> packed bf16 halves of
// d_out's u32 slot, xn -> bf16 in ws.
// ---------------------------------------------------------------------------
__global__ __launch_bounds__(256) void proj_k(
    const float* __restrict__ x,
    const float* __restrict__ Wir, const float* __restrict__ bir,
    const float* __restrict__ Wiz, const float* __restrict__ biz,
    const float* __restrict__ Win, const float* __restrict__ bin_,
    unsigned short* __restrict__ outp_u16,
    unsigned short* __restrict__ xn)
{
    const int nt   = blockIdx.x;            // 0..11
    const int gate = nt >> 2;
    const float* W  = (gate == 0) ? Wir : ((gate == 1) ? Wiz : Win);
    const float* bi = (gate == 0) ? bir : ((gate == 1) ? biz : bin_);
    const int jbase = (nt & 3) * 128;
    const int m0 = blockIdx.y * 128;
    const int t0 = blockIdx.y * 2;

    __shared__ __align__(16) unsigned short As[128][88];
    __shared__ __align__(16) unsigned short Bs[128][88];

    const int tid  = threadIdx.x;
    const int lane = tid & 63;
    const int wv   = tid >> 6;
    const int wm   = wv >> 1, wn = wv & 1;

    fx4 z4 = {0.f, 0.f, 0.f, 0.f};
    fx4 acc[4][4];
#pragma unroll
    for (int i = 0; i < 4; ++i)
#pragma unroll
        for (int j = 0; j < 4; ++j) acc[i][j] = z4;

    const int rr = tid >> 4;
    const int c4 = (tid & 15) * 4;

    for (int kb = 0; kb < 8; ++kb) {
        const int k0 = kb * 64;
#pragma unroll
        for (int pass = 0; pass < 8; ++pass) {
            const int r = pass * 16 + rr;
            const int bb = r & 63, tt = t0 + (r >> 6);
            const float* srcA = x + ((size_t)bb * S_ + tt) * D_ + k0 + c4;
            fx4 va = *(const fx4*)srcA;
            ux2 pa; pa.x = cvtpk(va.x, va.y); pa.y = cvtpk(va.z, va.w);
            *(ux2*)&As[r][c4] = pa;
            const float* srcB = W + (size_t)(jbase + r) * D_ + k0 + c4;
            fx4 vb = *(const fx4*)srcB;
            ux2 pb; pb.x = cvtpk(vb.x, vb.y); pb.y = cvtpk(vb.z, vb.w);
            *(ux2*)&Bs[r][c4] = pb;
        }
        __syncthreads();
#pragma unroll
        for (int kk = 0; kk < 64; kk += 32) {
            const int kloc = kk + (lane >> 4) * 8;
            sx8 af[4], bfv[4];
#pragma unroll
            for (int i = 0; i < 4; ++i)
                af[i] = *(const sx8*)&As[wm * 64 + i * 16 + (lane & 15)][kloc];
#pragma unroll
            for (int i = 0; i < 4; ++i)
                bfv[i] = *(const sx8*)&Bs[wn * 64 + i * 16 + (lane & 15)][kloc];
#pragma unroll
            for (int mi = 0; mi < 4; ++mi)
#pragma unroll
                for (int ni = 0; ni < 4; ++ni)
                    acc[mi][ni] = __builtin_amdgcn_mfma_f32_16x16x32_bf16(
                        af[mi], bfv[ni], acc[mi][ni], 0, 0, 0);
        }
        __syncthreads();
    }

    const int cold = lane & 15;
    const int rowq = (lane >> 4) * 4;
#pragma unroll
    for (int ni = 0; ni < 4; ++ni) {
        const int J = jbase + wn * 64 + ni * 16 + cold;
        const float bb = bi[J];
#pragma unroll
        for (int mi = 0; mi < 4; ++mi) {
#pragma unroll
            for (int reg = 0; reg < 4; ++reg) {
                const int R = m0 + wm * 64 + mi * 16 + rowq + reg;
                const int t = R >> 6, b = R & 63;
                const float val = acc[mi][ni][reg] + bb;
                const size_t e = (size_t)t * BH_ + (size_t)b * H_ + J;
                if (gate < 2) outp_u16[e * 2 + gate] = f2bf(val);
                else          xn[e] = f2bf(val);
            }
        }
    }
}

// ---------------------------------------------------------------------------
// Phase 2: persistent recurrent kernel = R11 (best, 3330us) + STORE ROLE-SPLIT.
// Diagnosis: poll's vmcnt(0) drained the polling lane's own publish + out[]
// store confirms (~2000+cy through IF) -> that, not data-wait, set the step.
// Fix: lanes with mp==m (8/wave, poll-idle) do ALL stores. All lanes write h
// to LDS (bf16 hst[p0] own-col + f32 hnew32); after lgkmcnt(0), free lanes
// read 8-col slices and issue 2 packet stores + 2 out[] f32 stores. Polling
// lanes carry ZERO outstanding stores -> poll vmcnt(0) = pure load RTT.
// Packet layout/consumer poll byte-identical to R11. Fast gate math
// (rcpf sigmoid, exp-based tanh) trims serial VALU at 1-wave/SIMD occupancy.
// ---------------------------------------------------------------------------
__global__ __launch_bounds__(256, 1) void gru_k(
    float* out,                              // read packed xr/xz, write h
    const unsigned short* __restrict__ xn,   // ws bf16
    unsigned int* pkt,                       // ws packet region (IF-coherent)
    const float* __restrict__ Whr, const float* __restrict__ bhr,
    const float* __restrict__ Whz, const float* __restrict__ bhz,
    const float* __restrict__ Whn, const float* __restrict__ bhn)
{
    const int tid = threadIdx.x, lane = tid & 63, wv = tid >> 6;
    const int bid = blockIdx.x;
    const int g = bid & 15, m = bid >> 4;
    const int c0 = m * 64;
    const int r = lane >> 4;                 // batch row within group
    const int jcol = c0 + wv * 16 + (lane & 15);
    const int mp = lane >> 3, s7 = lane & 7; // unpack / free-lane roles

    __shared__ __align__(16) unsigned short hst[2][2048];
    __shared__ __align__(16) float hnew32[4][4][16];   // [wave][batch][col16]
    for (int i = tid; i < 4096; i += 256) (&hst[0][0])[i] = 0;

    // Recurrent-weight B-fragments: j = jcol, k = kc*32 + kbase + q
    const int kbase = (lane >> 4) * 8;
    sx8 wfr[16], wfz[16], wfn[16];
#pragma unroll
    for (int kc = 0; kc < 16; ++kc) {
        const int k0 = kc * 32 + kbase;
        const float* pr = Whr + (size_t)jcol * H_ + k0;
        const float* pz = Whz + (size_t)jcol * H_ + k0;
        const float* pn = Whn + (size_t)jcol * H_ + k0;
        sx8 fr, fz, fn;
#pragma unroll
        for (int q = 0; q < 8; ++q) {
            fr[q] = (short)f2bf(pr[q]);
            fz[q] = (short)f2bf(pz[q]);
            fn[q] = (short)f2bf(pn[q]);
        }
        wfr[kc] = fr; wfz[kc] = fz; wfn[kc] = fn;
    }
    const float bhr_v = bhr[jcol], bhz_v = bhz[jcol], bhn_v = bhn[jcol];

    const size_t xoff = (size_t)(4 * g + r) * H_ + jcol;
    unsigned int   xz_c  = __float_as_uint(out[xoff]);   // t=0 packed xr|xz
    unsigned short xnn_c = xn[xoff];
    float hprev = 0.f;
    __syncthreads();

    for (int t = 0; t < S_; ++t) {
        const int p1 = (t - 1) & 1, p0 = t & 1;

        // ---- poll + unpack h(t-1) from the other 7 members ----
        // Polling lanes have NO outstanding stores: vmcnt(0) = load RTT only.
        if (t > 0 && mp != m) {
            const unsigned int ex = (unsigned int)(t - 1);
            const char* pb = (const char*)pkt +
                ((((size_t)(p1 * 64 + 4 * g + wv)) * NMEM + mp) * 256
                 + (size_t)s7 * 32);
            ux4 q0, q1;
            for (;;) {
                asm volatile(
                    "global_load_dwordx4 %0, %2, off sc0 sc1\n\t"
                    "global_load_dwordx4 %1, %2, off offset:16 sc0 sc1\n\t"
                    "s_waitcnt vmcnt(0)"
                    : "=&v"(q0), "=&v"(q1) : "v"(pb) : "memory");
                if ((((q0.x ^ ex) | (q0.w ^ ex)) |
                     ((q1.x ^ ex) | (q1.w ^ ex))) == 0u) break;
            }
            const int unit = (mp * 2 + (s7 >> 2)) * 16 + wv * 4 + (s7 & 3);
            ux4 w; w.x = q0.y; w.y = q0.z; w.z = q1.y; w.w = q1.z;
            *(ux4*)&hst[p1][unit * 8] = w;
        }

        // ---- x prefetch for t+1, AFTER the poll drain (R9-proven) ----
        unsigned int xz_n = xz_c; unsigned short xnn_n = xnn_c;
        if (t + 1 < S_) {
            xz_n  = __float_as_uint(out[(size_t)(t + 1) * BH_ + xoff]);
            xnn_n = xn[(size_t)(t + 1) * BH_ + xoff];
        }
        BAR();   // hst[p1] ready for all waves (lgkm only, no vmem drain)

        // ---- matvec (48 MFMA) + gates (all 64 lanes) ----
        fx4 ar = {0.f,0.f,0.f,0.f}, az = {0.f,0.f,0.f,0.f}, an = {0.f,0.f,0.f,0.f};
#pragma unroll
        for (int kc = 0; kc < 16; ++kc) {
            sx8 a = *(const sx8*)&hst[p1][(kc * 16 + (lane & 3) * 4 + (lane >> 4)) * 8];
            ar = __builtin_amdgcn_mfma_f32_16x16x32_bf16(a, wfr[kc], ar, 0, 0, 0);
            az = __builtin_amdgcn_mfma_f32_16x16x32_bf16(a, wfz[kc], az, 0, 0, 0);
            an = __builtin_amdgcn_mfma_f32_16x16x32_bf16(a, wfn[kc], an, 0, 0, 0);
        }
        const float sr = (r == 0) ? ar[0] : (r == 1) ? ar[1] : (r == 2) ? ar[2] : ar[3];
        const float sz = (r == 0) ? az[0] : (r == 1) ? az[1] : (r == 2) ? az[2] : az[3];
        const float sn = (r == 0) ? an[0] : (r == 1) ? an[1] : (r == 2) ? an[2] : an[3];
        const float arx = sr + bf2f((unsigned short)(xz_c & 0xffffu)) + bhr_v;
        const float azx = sz + bf2f((unsigned short)(xz_c >> 16)) + bhz_v;
        // fast sigmoid / tanh (rcpf ~1ulp; saturation exact at +-inf)
        const float rg = __builtin_amdgcn_rcpf(1.f + __expf(-arx));
        const float zg = __builtin_amdgcn_rcpf(1.f + __expf(-azx));
        const float ti = bf2f(xnn_c) + rg * (sn + bhn_v);
        const float nn = 1.f - 2.f * __builtin_amdgcn_rcpf(__expf(2.f * ti) + 1.f);
        const float hv = (1.f - zg) * nn + zg * hprev;
        hprev = hv;

        // ---- all lanes stage h into LDS (bf16 for exchange/matvec, f32 for out) ----
        {
            const int unit = ((jcol >> 5) << 4) + r * 4 + ((jcol >> 3) & 3);
            hst[p0][unit * 8 + (jcol & 7)] = f2bf(hv);
            hnew32[wv][r][lane & 15] = hv;
        }
        asm volatile("s_waitcnt lgkmcnt(0)" ::: "memory");  // same-wave writes visible

        // ---- free lanes (mp==m): ALL stores (packets + out f32) ----
        if (mp == m) {
            const int f  = s7;               // 0..7
            const int b  = f >> 1;           // batch within group
            const int q2 = (f & 1) * 2;      // quad-pair base within wave
            const int k0 = c0 + wv * 16 + q2 * 4;    // 8-aligned col base
            const int unit = ((k0 >> 5) << 4) + b * 4 + ((k0 >> 3) & 3);
            ux4 pay = *(const ux4*)&hst[p0][unit * 8];   // 8 bf16 = cols k0..k0+8
            const unsigned int tag = (unsigned int)t;
            ux4 pkA; pkA.x = tag; pkA.y = pay.x; pkA.z = pay.y; pkA.w = tag;
            ux4 pkB; pkB.x = tag; pkB.y = pay.z; pkB.z = pay.w; pkB.w = tag;
            char* ad = (char*)pkt +
                ((((size_t)(p0 * 64 + 4 * g + b)) * NMEM + m) * 256
                 + (size_t)(wv * 4 + q2) * 16);
            asm volatile("global_store_dwordx4 %0, %2, off sc0 sc1\n\t"
                         "global_store_dwordx4 %1, %3, off sc0 sc1"
                         :: "v"(ad), "v"(ad + 16), "v"(pkA), "v"(pkB) : "memory");
            // f32 h outputs for cols k0..k0+8, batch b
            const float* hsrc = &hnew32[wv][b][q2 * 4];
            fx4 o0 = *(const fx4*)hsrc;
            fx4 o1 = *(const fx4*)(hsrc + 4);
            float* op = out + (size_t)t * BH_ + (size_t)(4 * g + b) * H_ + k0;
            *(fx4*)op = o0; *(fx4*)(op + 4) = o1;
            if (t == S_ - 1) {
                float* fp = out + (size_t)S_ * BH_ + (size_t)(4 * g + b) * H_ + k0;
                *(fx4*)fp = o0; *(fx4*)(fp + 4) = o1;
            }
        }
        xz_c = xz_n; xnn_c = xnn_n;
    }
}

extern "C" void kernel_launch(void* const* d_in, const int* in_sizes, int n_in,
                              void* d_out, int out_size, void* d_ws, size_t ws_size,
                              hipStream_t stream) {
    (void)in_sizes; (void)n_in; (void)out_size; (void)ws_size;
    const float* x    = (const float*)d_in[0];
    const float* Wir  = (const float*)d_in[1];
    const float* bir  = (const float*)d_in[2];
    const float* Whr  = (const float*)d_in[3];
    const float* bhr  = (const float*)d_in[4];
    const float* Wiz  = (const float*)d_in[5];
    const float* biz  = (const float*)d_in[6];
    const float* Whz  = (const float*)d_in[7];
    const float* bhz  = (const float*)d_in[8];
    const float* Win  = (const float*)d_in[9];
    const float* bin_ = (const float*)d_in[10];
    const float* Whn  = (const float*)d_in[11];
    const float* bhn  = (const float*)d_in[12];

    unsigned short* xn = (unsigned short*)d_ws;                              // 128 MiB
    unsigned int* pkt = (unsigned int*)((char*)d_ws + (size_t)S_ * BH_ * 2); // 256 KiB

    proj_k<<<dim3(12, 1024, 1), 256, 0, stream>>>(
        x, Wir, bir, Wiz, biz, Win, bin_, (unsigned short*)d_out, xn);
    gru_k<<<dim3(128, 1, 1), 256, 0, stream>>>(
        (float*)d_out, xn, pkt, Whr, bhr, Whz, bhz, Whn, bhn);
}

// Round 14
// 3855.577 us; speedup vs baseline: 1.0498x; 1.0498x over previous
//
#include <hip/hip_runtime.h>

#define S_ 2048
#define B_ 64
#define D_ 512
#define H_ 512
#define BH_ (B_*H_)
#define NMEM 8
#define NGRU 128
#define MGK 0xC0DE600Du

typedef __attribute__((ext_vector_type(4))) float fx4;
typedef __attribute__((ext_vector_type(8))) short sx8;
typedef __attribute__((ext_vector_type(4))) unsigned int ux4;
typedef __attribute__((ext_vector_type(2))) unsigned int ux2;

__device__ __forceinline__ unsigned short f2bf(float f) {
    union { float f; unsigned int u; } v; v.f = f;
    return (unsigned short)((v.u + 0x7fffu + ((v.u >> 16) & 1u)) >> 16);
}
__device__ __forceinline__ float bf2f(unsigned short b) {
    union { float f; unsigned int u; } v; v.u = ((unsigned int)b) << 16;
    return v.f;
}
__device__ __forceinline__ unsigned int cvtpk(float a, float b) {
    unsigned int r;
    asm("v_cvt_pk_bf16_f32 %0, %1, %2" : "=v"(r) : "v"(a), "v"(b));
    return r;
}

// raw barrier WITHOUT vmcnt drain
#define BAR() asm volatile("s_waitcnt lgkmcnt(0)\n\ts_barrier" ::: "memory")

#define ALL12(a,b,c) ((((a.x^MGK)|(a.y^MGK)|(a.z^MGK)|(a.w^MGK)) | \
                       ((b.x^MGK)|(b.y^MGK)|(b.z^MGK)|(b.w^MGK)) | \
                       ((c.x^MGK)|(c.y^MGK)|(c.z^MGK)|(c.w^MGK))) == 0u)

// ---------------------------------------------------------------------------
// Fused kernel. Blocks [0,128): persistent gru (R11 body, proven 3330us).
// Blocks [128, 128+12288): proj (R11 body) + release-fence + MAGIC flag.
// xflag is ZEROED each launch via hipMemsetAsync (R6-proven capture-safe) ->
// the flag handshake is launch-local; replay-safe by construction.
// ---------------------------------------------------------------------------
__global__ __launch_bounds__(256, 1) void fused_k(
    const float* __restrict__ x,
    const float* __restrict__ Wir, const float* __restrict__ bir,
    const float* __restrict__ Wiz, const float* __restrict__ biz,
    const float* __restrict__ Win, const float* __restrict__ bin_,
    const float* __restrict__ Whr, const float* __restrict__ bhr,
    const float* __restrict__ Whz, const float* __restrict__ bhz,
    const float* __restrict__ Whn, const float* __restrict__ bhn,
    float* out, unsigned short* xn, unsigned int* pkt, unsigned int* xflag)
{
    __shared__ __align__(16) unsigned short As[128][88];
    __shared__ __align__(16) unsigned short Bs[128][88];
    __shared__ __align__(16) unsigned short hst[2][2048];

    const int tid  = threadIdx.x;
    const int bid  = blockIdx.x;
    const int lane = tid & 63;
    const int wv   = tid >> 6;

    if (bid >= NGRU) {
        // ================= proj path =================
        const int pb   = bid - NGRU;
        const int nt   = pb % 12;           // fastest -> 12 n-tiles share x m-tile
        const int Y    = pb / 12;           // ascending -> t ascending
        const int gate = nt >> 2;
        const float* W  = (gate == 0) ? Wir : ((gate == 1) ? Wiz : Win);
        const float* bi = (gate == 0) ? bir : ((gate == 1) ? biz : bin_);
        const int jbase = (nt & 3) * 128;
        const int m0 = Y * 128;
        const int t0 = Y * 2;

        const int wm = wv >> 1, wn = wv & 1;

        fx4 z4 = {0.f, 0.f, 0.f, 0.f};
        fx4 acc[4][4];
#pragma unroll
        for (int i = 0; i < 4; ++i)
#pragma unroll
            for (int j = 0; j < 4; ++j) acc[i][j] = z4;

        const int rr = tid >> 4;
        const int c4 = (tid & 15) * 4;

        for (int kb = 0; kb < 8; ++kb) {
            const int k0 = kb * 64;
#pragma unroll
            for (int pass = 0; pass < 8; ++pass) {
                const int r = pass * 16 + rr;
                const int bb = r & 63, tt = t0 + (r >> 6);
                const float* srcA = x + ((size_t)bb * S_ + tt) * D_ + k0 + c4;
                fx4 va = *(const fx4*)srcA;
                ux2 pa; pa.x = cvtpk(va.x, va.y); pa.y = cvtpk(va.z, va.w);
                *(ux2*)&As[r][c4] = pa;
                const float* srcB = W + (size_t)(jbase + r) * D_ + k0 + c4;
                fx4 vb = *(const fx4*)srcB;
                ux2 pb2; pb2.x = cvtpk(vb.x, vb.y); pb2.y = cvtpk(vb.z, vb.w);
                *(ux2*)&Bs[r][c4] = pb2;
            }
            __syncthreads();
#pragma unroll
            for (int kk = 0; kk < 64; kk += 32) {
                const int kloc = kk + (lane >> 4) * 8;
                sx8 af[4], bfv[4];
#pragma unroll
                for (int i = 0; i < 4; ++i)
                    af[i] = *(const sx8*)&As[wm * 64 + i * 16 + (lane & 15)][kloc];
#pragma unroll
                for (int i = 0; i < 4; ++i)
                    bfv[i] = *(const sx8*)&Bs[wn * 64 + i * 16 + (lane & 15)][kloc];
#pragma unroll
                for (int mi = 0; mi < 4; ++mi)
#pragma unroll
                    for (int ni = 0; ni < 4; ++ni)
                        acc[mi][ni] = __builtin_amdgcn_mfma_f32_16x16x32_bf16(
                            af[mi], bfv[ni], acc[mi][ni], 0, 0, 0);
            }
            __syncthreads();
        }

        unsigned short* outp_u16 = (unsigned short*)out;
        const int cold = lane & 15;
        const int rowq = (lane >> 4) * 4;
#pragma unroll
        for (int ni = 0; ni < 4; ++ni) {
            const int J = jbase + wn * 64 + ni * 16 + cold;
            const float bb = bi[J];
#pragma unroll
            for (int mi = 0; mi < 4; ++mi) {
#pragma unroll
                for (int reg = 0; reg < 4; ++reg) {
                    const int R = m0 + wm * 64 + mi * 16 + rowq + reg;
                    const int t = R >> 6, b = R & 63;
                    const float val = acc[mi][ni][reg] + bb;
                    const size_t e = (size_t)t * BH_ + (size_t)b * H_ + J;
                    if (gate < 2) outp_u16[e * 2 + gate] = f2bf(val);
                    else          xn[e] = f2bf(val);
                }
            }
        }
        // release: all block stores ack'd -> L2 writeback -> MAGIC flag
        __syncthreads();
        if (tid == 0) {
            __threadfence();                 // device-scope: L2 wb on CDNA
            unsigned int mg = MGK;
            unsigned int* fa = xflag + (size_t)Y * 12 + nt;
            asm volatile("global_store_dword %0, %1, off sc0 sc1"
                         :: "v"(fa), "v"(mg) : "memory");
        }
        return;
    }

    // ================= gru path (R11 + flag pipeline) =================
    const int g = bid & 15, m = bid >> 4;
    const int c0 = m * 64;
    const int r = lane >> 4;
    const int jcol = c0 + wv * 16 + (lane & 15);
    const int mp = lane >> 3, s7 = lane & 7;

    for (int i = tid; i < 4096; i += 256) (&hst[0][0])[i] = 0;

    const int kbase = (lane >> 4) * 8;
    sx8 wfr[16], wfz[16], wfn[16];
#pragma unroll
    for (int kc = 0; kc < 16; ++kc) {
        const int k0 = kc * 32 + kbase;
        const float* pr = Whr + (size_t)jcol * H_ + k0;
        const float* pz = Whz + (size_t)jcol * H_ + k0;
        const float* pn = Whn + (size_t)jcol * H_ + k0;
        sx8 fr, fz, fn;
#pragma unroll
        for (int q = 0; q < 8; ++q) {
            fr[q] = (short)f2bf(pr[q]);
            fz[q] = (short)f2bf(pz[q]);
            fn[q] = (short)f2bf(pn[q]);
        }
        wfr[kc] = fr; wfz[kc] = fz; wfn[kc] = fn;
    }
    const float bhr_v = bhr[jcol], bhz_v = bhz[jcol], bhn_v = bhn[jcol];

    ux4 fr0 = {0,0,0,0}, fr1 = {0,0,0,0}, fr2 = {0,0,0,0};
    int Ymax = 0;

    // wait for Y=0 (t=0,1 x data) before first x touch
    {
        const unsigned int* f0 = xflag;
        for (;;) {
            asm volatile(
                "global_load_dwordx4 %0, %3, off sc0 sc1\n\t"
                "global_load_dwordx4 %1, %3, off offset:16 sc0 sc1\n\t"
                "global_load_dwordx4 %2, %3, off offset:32 sc0 sc1\n\t"
                "s_waitcnt vmcnt(0)"
                : "=&v"(fr0), "=&v"(fr1), "=&v"(fr2) : "v"(f0) : "memory");
            if (ALL12(fr0, fr1, fr2)) break;
            __builtin_amdgcn_s_sleep(8);
        }
    }

    const size_t xoff = (size_t)(4 * g + r) * H_ + jcol;
    unsigned int   xz_c  = __float_as_uint(out[xoff]);
    unsigned short xnn_c = xn[xoff];
    float hprev = 0.f;
    __syncthreads();

    for (int t = 0; t < S_; ++t) {
        const int p1 = (t - 1) & 1, p0 = t & 1;

        // ---- poll + unpack h(t-1) ----
        if (t > 0 && mp != m) {
            const unsigned int ex = (unsigned int)(t - 1);
            const char* pb = (const char*)pkt +
                ((((size_t)(p1 * 64 + 4 * g + wv)) * NMEM + mp) * 256
                 + (size_t)s7 * 32);
            ux4 q0, q1;
            for (;;) {
                asm volatile(
                    "global_load_dwordx4 %0, %2, off sc0 sc1\n\t"
                    "global_load_dwordx4 %1, %2, off offset:16 sc0 sc1\n\t"
                    "s_waitcnt vmcnt(0)"
                    : "=&v"(q0), "=&v"(q1) : "v"(pb) : "memory");
                if ((((q0.x ^ ex) | (q0.w ^ ex)) |
                     ((q1.x ^ ex) | (q1.w ^ ex))) == 0u) break;
            }
            const int unit = (mp * 2 + (s7 >> 2)) * 16 + wv * 4 + (s7 & 3);
            ux4 w; w.x = q0.y; w.y = q0.z; w.z = q1.y; w.w = q1.z;
            *(ux4*)&hst[p1][unit * 8] = w;
        }
        // pin: fr regs valid for ALL lanes (drains free lanes' old loads/stores)
        asm volatile("s_waitcnt vmcnt(0)"
                     : "+v"(fr0), "+v"(fr1), "+v"(fr2) :: "memory");

        // ---- x prefetch for t+1, flag-gated (pipelined check) ----
        unsigned int xz_n = xz_c; unsigned short xnn_n = xnn_c;
        if (t + 1 < S_) {
            const int Y1 = (t + 1) >> 1;
            if (Y1 > Ymax) {
                if (!ALL12(fr0, fr1, fr2)) {   // rare: gru caught proj
                    const unsigned int* fp1 = xflag + (size_t)Y1 * 12;
                    for (;;) {
                        asm volatile(
                            "global_load_dwordx4 %0, %3, off sc0 sc1\n\t"
                            "global_load_dwordx4 %1, %3, off offset:16 sc0 sc1\n\t"
                            "global_load_dwordx4 %2, %3, off offset:32 sc0 sc1\n\t"
                            "s_waitcnt vmcnt(0)"
                            : "=&v"(fr0), "=&v"(fr1), "=&v"(fr2)
                            : "v"(fp1) : "memory");
                        if (ALL12(fr0, fr1, fr2)) break;
                        __builtin_amdgcn_s_sleep(2);
                    }
                }
                Ymax = Y1;
            }
            xz_n  = __float_as_uint(out[(size_t)(t + 1) * BH_ + xoff]);
            xnn_n = xn[(size_t)(t + 1) * BH_ + xoff];
            // fire-and-forget flag loads for the NEXT pair (verified next step)
            const int Yf = (Y1 + 1 < 1024) ? Y1 + 1 : 1023;
            const unsigned int* fpn = xflag + (size_t)Yf * 12;
            asm volatile(
                "global_load_dwordx4 %0, %3, off sc0 sc1\n\t"
                "global_load_dwordx4 %1, %3, off offset:16 sc0 sc1\n\t"
                "global_load_dwordx4 %2, %3, off offset:32 sc0 sc1"
                : "=&v"(fr0), "=&v"(fr1), "=&v"(fr2) : "v"(fpn) : "memory");
        }
        BAR();

        // ---- matvec (48 MFMA) + gates ----
        fx4 ar = {0.f,0.f,0.f,0.f}, az = {0.f,0.f,0.f,0.f}, an = {0.f,0.f,0.f,0.f};
#pragma unroll
        for (int kc = 0; kc < 16; ++kc) {
            sx8 a = *(const sx8*)&hst[p1][(kc * 16 + (lane & 3) * 4 + (lane >> 4)) * 8];
            ar = __builtin_amdgcn_mfma_f32_16x16x32_bf16(a, wfr[kc], ar, 0, 0, 0);
            az = __builtin_amdgcn_mfma_f32_16x16x32_bf16(a, wfz[kc], az, 0, 0, 0);
            an = __builtin_amdgcn_mfma_f32_16x16x32_bf16(a, wfn[kc], an, 0, 0, 0);
        }
        const float sr = (r == 0) ? ar[0] : (r == 1) ? ar[1] : (r == 2) ? ar[2] : ar[3];
        const float sz = (r == 0) ? az[0] : (r == 1) ? az[1] : (r == 2) ? az[2] : az[3];
        const float sn = (r == 0) ? an[0] : (r == 1) ? an[1] : (r == 2) ? an[2] : an[3];
        const float arx = sr + bf2f((unsigned short)(xz_c & 0xffffu)) + bhr_v;
        const float azx = sz + bf2f((unsigned short)(xz_c >> 16)) + bhz_v;
        const float rg = 1.f / (1.f + __expf(-arx));
        const float zg = 1.f / (1.f + __expf(-azx));
        const float nn = tanhf(bf2f(xnn_c) + rg * (sn + bhn_v));
        const float hv = (1.f - zg) * nn + zg * hprev;
        hprev = hv;

        // ---- publish own cols from registers (DPP quad pack) ----
        {
            const unsigned int hu1 = (unsigned int)__builtin_amdgcn_mov_dpp(
                (int)__float_as_uint(hv), 0xB1, 0xF, 0xF, true);
            const unsigned int pk01 = cvtpk(hv, __uint_as_float(hu1));
            const unsigned int pk23 = (unsigned int)__builtin_amdgcn_mov_dpp(
                (int)pk01, 0x4E, 0xF, 0xF, true);
            if ((lane & 3) == 0) {
                const int qg = wv * 4 + ((lane & 15) >> 2);
                const unsigned int tag = (unsigned int)t;
                ux4 pk4; pk4.x = tag; pk4.y = pk01; pk4.z = pk23; pk4.w = tag;
                char* addr = (char*)pkt +
                    ((((size_t)(p0 * 64 + 4 * g + r)) * NMEM + m) * 256
                     + (size_t)qg * 16);
                asm volatile("global_store_dwordx4 %0, %1, off sc0 sc1"
                             :: "v"(addr), "v"(pk4) : "memory");
            }
        }
        {
            const int unit = ((jcol >> 5) << 4) + r * 4 + ((jcol >> 3) & 3);
            hst[p0][unit * 8 + (jcol & 7)] = f2bf(hv);
        }
        out[(size_t)t * BH_ + xoff] = hv;
        if (t == S_ - 1) out[(size_t)S_ * BH_ + xoff] = hv;
        xz_c = xz_n; xnn_c = xnn_n;
    }
}

extern "C" void kernel_launch(void* const* d_in, const int* in_sizes, int n_in,
                              void* d_out, int out_size, void* d_ws, size_t ws_size,
                              hipStream_t stream) {
    (void)in_sizes; (void)n_in; (void)out_size; (void)ws_size;
    const float* x    = (const float*)d_in[0];
    const float* Wir  = (const float*)d_in[1];
    const float* bir  = (const float*)d_in[2];
    const float* Whr  = (const float*)d_in[3];
    const float* bhr  = (const float*)d_in[4];
    const float* Wiz  = (const float*)d_in[5];
    const float* biz  = (const float*)d_in[6];
    const float* Whz  = (const float*)d_in[7];
    const float* bhz  = (const float*)d_in[8];
    const float* Win  = (const float*)d_in[9];
    const float* bin_ = (const float*)d_in[10];
    const float* Whn  = (const float*)d_in[11];
    const float* bhn  = (const float*)d_in[12];

    unsigned short* xn = (unsigned short*)d_ws;                      // 128 MiB
    char* base = (char*)d_ws + (size_t)S_ * BH_ * 2;
    unsigned int* pkt   = (unsigned int*)base;                       // 256 KiB
    unsigned int* xflag = (unsigned int*)(base + 256 * 1024);        // 48 KiB

    // Clear the launch-local handshake flags EVERY call (replay-safe; R6
    // proved hipMemsetAsync is graph-capture-safe on this harness).
    hipMemsetAsync(xflag, 0, 12 * 1024 * sizeof(unsigned int), stream);

    fused_k<<<dim3(NGRU + 12 * 1024, 1, 1), 256, 0, stream>>>(
        x, Wir, bir, Wiz, biz, Win, bin_,
        Whr, bhr, Whz, bhz, Whn, bhn,
        (float*)d_out, xn, pkt, xflag);
}

// Round 15
// 3737.449 us; speedup vs baseline: 1.0830x; 1.0316x over previous
//
#include <hip/hip_runtime.h>

#define S_ 2048
#define B_ 64
#define D_ 512
#define H_ 512
#define BH_ (B_*H_)
#define NMEM 8
#define NGRU 128
#define MGK 0xC0DE600Du

typedef __attribute__((ext_vector_type(4))) float fx4;
typedef __attribute__((ext_vector_type(8))) short sx8;
typedef __attribute__((ext_vector_type(4))) unsigned int ux4;
typedef __attribute__((ext_vector_type(2))) unsigned int ux2;

__device__ __forceinline__ unsigned short f2bf(float f) {
    union { float f; unsigned int u; } v; v.f = f;
    return (unsigned short)((v.u + 0x7fffu + ((v.u >> 16) & 1u)) >> 16);
}
__device__ __forceinline__ float bf2f(unsigned short b) {
    union { float f; unsigned int u; } v; v.u = ((unsigned int)b) << 16;
    return v.f;
}
__device__ __forceinline__ unsigned int cvtpk(float a, float b) {
    unsigned int r;
    asm("v_cvt_pk_bf16_f32 %0, %1, %2" : "=v"(r) : "v"(a), "v"(b));
    return r;
}

// raw barrier WITHOUT vmcnt drain
#define BAR() asm volatile("s_waitcnt lgkmcnt(0)\n\ts_barrier" ::: "memory")

#define ALL12(a,b,c) ((((a.x^MGK)|(a.y^MGK)|(a.z^MGK)|(a.w^MGK)) | \
                       ((b.x^MGK)|(b.y^MGK)|(b.z^MGK)|(b.w^MGK)) | \
                       ((c.x^MGK)|(c.y^MGK)|(c.z^MGK)|(c.w^MGK))) == 0u)

// ---------------------------------------------------------------------------
// Fused kernel (R14, passed @3856us) + two contention cuts on the gru path:
//  (1) s_setprio(2) for gru waves (proj stays 0): CU-scheduler favors the
//      latency-critical persistent waves over co-resident proj waves.
//  (2) fast gate math (rcpf sigmoid / exp-form tanh, R12-validated bits):
//      removes ~200cy serial VALU from the per-step critical path.
// ---------------------------------------------------------------------------
__global__ __launch_bounds__(256, 1) void fused_k(
    const float* __restrict__ x,
    const float* __restrict__ Wir, const float* __restrict__ bir,
    const float* __restrict__ Wiz, const float* __restrict__ biz,
    const float* __restrict__ Win, const float* __restrict__ bin_,
    const float* __restrict__ Whr, const float* __restrict__ bhr,
    const float* __restrict__ Whz, const float* __restrict__ bhz,
    const float* __restrict__ Whn, const float* __restrict__ bhn,
    float* out, unsigned short* xn, unsigned int* pkt, unsigned int* xflag)
{
    __shared__ __align__(16) unsigned short As[128][88];
    __shared__ __align__(16) unsigned short Bs[128][88];
    __shared__ __align__(16) unsigned short hst[2][2048];

    const int tid  = threadIdx.x;
    const int bid  = blockIdx.x;
    const int lane = tid & 63;
    const int wv   = tid >> 6;

    if (bid >= NGRU) {
        // ================= proj path =================
        const int pb   = bid - NGRU;
        const int nt   = pb % 12;           // fastest -> 12 n-tiles share x m-tile
        const int Y    = pb / 12;           // ascending -> t ascending
        const int gate = nt >> 2;
        const float* W  = (gate == 0) ? Wir : ((gate == 1) ? Wiz : Win);
        const float* bi = (gate == 0) ? bir : ((gate == 1) ? biz : bin_);
        const int jbase = (nt & 3) * 128;
        const int m0 = Y * 128;
        const int t0 = Y * 2;

        const int wm = wv >> 1, wn = wv & 1;

        fx4 z4 = {0.f, 0.f, 0.f, 0.f};
        fx4 acc[4][4];
#pragma unroll
        for (int i = 0; i < 4; ++i)
#pragma unroll
            for (int j = 0; j < 4; ++j) acc[i][j] = z4;

        const int rr = tid >> 4;
        const int c4 = (tid & 15) * 4;

        for (int kb = 0; kb < 8; ++kb) {
            const int k0 = kb * 64;
#pragma unroll
            for (int pass = 0; pass < 8; ++pass) {
                const int r = pass * 16 + rr;
                const int bb = r & 63, tt = t0 + (r >> 6);
                const float* srcA = x + ((size_t)bb * S_ + tt) * D_ + k0 + c4;
                fx4 va = *(const fx4*)srcA;
                ux2 pa; pa.x = cvtpk(va.x, va.y); pa.y = cvtpk(va.z, va.w);
                *(ux2*)&As[r][c4] = pa;
                const float* srcB = W + (size_t)(jbase + r) * D_ + k0 + c4;
                fx4 vb = *(const fx4*)srcB;
                ux2 pb2; pb2.x = cvtpk(vb.x, vb.y); pb2.y = cvtpk(vb.z, vb.w);
                *(ux2*)&Bs[r][c4] = pb2;
            }
            __syncthreads();
#pragma unroll
            for (int kk = 0; kk < 64; kk += 32) {
                const int kloc = kk + (lane >> 4) * 8;
                sx8 af[4], bfv[4];
#pragma unroll
                for (int i = 0; i < 4; ++i)
                    af[i] = *(const sx8*)&As[wm * 64 + i * 16 + (lane & 15)][kloc];
#pragma unroll
                for (int i = 0; i < 4; ++i)
                    bfv[i] = *(const sx8*)&Bs[wn * 64 + i * 16 + (lane & 15)][kloc];
#pragma unroll
                for (int mi = 0; mi < 4; ++mi)
#pragma unroll
                    for (int ni = 0; ni < 4; ++ni)
                        acc[mi][ni] = __builtin_amdgcn_mfma_f32_16x16x32_bf16(
                            af[mi], bfv[ni], acc[mi][ni], 0, 0, 0);
            }
            __syncthreads();
        }

        unsigned short* outp_u16 = (unsigned short*)out;
        const int cold = lane & 15;
        const int rowq = (lane >> 4) * 4;
#pragma unroll
        for (int ni = 0; ni < 4; ++ni) {
            const int J = jbase + wn * 64 + ni * 16 + cold;
            const float bb = bi[J];
#pragma unroll
            for (int mi = 0; mi < 4; ++mi) {
#pragma unroll
                for (int reg = 0; reg < 4; ++reg) {
                    const int R = m0 + wm * 64 + mi * 16 + rowq + reg;
                    const int t = R >> 6, b = R & 63;
                    const float val = acc[mi][ni][reg] + bb;
                    const size_t e = (size_t)t * BH_ + (size_t)b * H_ + J;
                    if (gate < 2) outp_u16[e * 2 + gate] = f2bf(val);
                    else          xn[e] = f2bf(val);
                }
            }
        }
        // release: all block stores ack'd -> L2 writeback -> MAGIC flag
        __syncthreads();
        if (tid == 0) {
            __threadfence();                 // device-scope: L2 wb on CDNA
            unsigned int mg = MGK;
            unsigned int* fa = xflag + (size_t)Y * 12 + nt;
            asm volatile("global_store_dword %0, %1, off sc0 sc1"
                         :: "v"(fa), "v"(mg) : "memory");
        }
        return;
    }

    // ================= gru path (R14 + setprio + fast gates) =================
    __builtin_amdgcn_s_setprio(2);           // favor latency-critical waves
    const int g = bid & 15, m = bid >> 4;
    const int c0 = m * 64;
    const int r = lane >> 4;
    const int jcol = c0 + wv * 16 + (lane & 15);
    const int mp = lane >> 3, s7 = lane & 7;

    for (int i = tid; i < 4096; i += 256) (&hst[0][0])[i] = 0;

    const int kbase = (lane >> 4) * 8;
    sx8 wfr[16], wfz[16], wfn[16];
#pragma unroll
    for (int kc = 0; kc < 16; ++kc) {
        const int k0 = kc * 32 + kbase;
        const float* pr = Whr + (size_t)jcol * H_ + k0;
        const float* pz = Whz + (size_t)jcol * H_ + k0;
        const float* pn = Whn + (size_t)jcol * H_ + k0;
        sx8 fr, fz, fn;
#pragma unroll
        for (int q = 0; q < 8; ++q) {
            fr[q] = (short)f2bf(pr[q]);
            fz[q] = (short)f2bf(pz[q]);
            fn[q] = (short)f2bf(pn[q]);
        }
        wfr[kc] = fr; wfz[kc] = fz; wfn[kc] = fn;
    }
    const float bhr_v = bhr[jcol], bhz_v = bhz[jcol], bhn_v = bhn[jcol];

    ux4 fr0 = {0,0,0,0}, fr1 = {0,0,0,0}, fr2 = {0,0,0,0};
    int Ymax = 0;

    // wait for Y=0 (t=0,1 x data) before first x touch
    {
        const unsigned int* f0 = xflag;
        for (;;) {
            asm volatile(
                "global_load_dwordx4 %0, %3, off sc0 sc1\n\t"
                "global_load_dwordx4 %1, %3, off offset:16 sc0 sc1\n\t"
                "global_load_dwordx4 %2, %3, off offset:32 sc0 sc1\n\t"
                "s_waitcnt vmcnt(0)"
                : "=&v"(fr0), "=&v"(fr1), "=&v"(fr2) : "v"(f0) : "memory");
            if (ALL12(fr0, fr1, fr2)) break;
            __builtin_amdgcn_s_sleep(8);
        }
    }

    const size_t xoff = (size_t)(4 * g + r) * H_ + jcol;
    unsigned int   xz_c  = __float_as_uint(out[xoff]);
    unsigned short xnn_c = xn[xoff];
    float hprev = 0.f;
    __syncthreads();

    for (int t = 0; t < S_; ++t) {
        const int p1 = (t - 1) & 1, p0 = t & 1;

        // ---- poll + unpack h(t-1) ----
        if (t > 0 && mp != m) {
            const unsigned int ex = (unsigned int)(t - 1);
            const char* pb = (const char*)pkt +
                ((((size_t)(p1 * 64 + 4 * g + wv)) * NMEM + mp) * 256
                 + (size_t)s7 * 32);
            ux4 q0, q1;
            for (;;) {
                asm volatile(
                    "global_load_dwordx4 %0, %2, off sc0 sc1\n\t"
                    "global_load_dwordx4 %1, %2, off offset:16 sc0 sc1\n\t"
                    "s_waitcnt vmcnt(0)"
                    : "=&v"(q0), "=&v"(q1) : "v"(pb) : "memory");
                if ((((q0.x ^ ex) | (q0.w ^ ex)) |
                     ((q1.x ^ ex) | (q1.w ^ ex))) == 0u) break;
            }
            const int unit = (mp * 2 + (s7 >> 2)) * 16 + wv * 4 + (s7 & 3);
            ux4 w; w.x = q0.y; w.y = q0.z; w.z = q1.y; w.w = q1.z;
            *(ux4*)&hst[p1][unit * 8] = w;
        }
        // pin: fr regs valid for ALL lanes (drains free lanes' old loads/stores)
        asm volatile("s_waitcnt vmcnt(0)"
                     : "+v"(fr0), "+v"(fr1), "+v"(fr2) :: "memory");

        // ---- x prefetch for t+1, flag-gated (pipelined check) ----
        unsigned int xz_n = xz_c; unsigned short xnn_n = xnn_c;
        if (t + 1 < S_) {
            const int Y1 = (t + 1) >> 1;
            if (Y1 > Ymax) {
                if (!ALL12(fr0, fr1, fr2)) {   // rare: gru caught proj
                    const unsigned int* fp1 = xflag + (size_t)Y1 * 12;
                    for (;;) {
                        asm volatile(
                            "global_load_dwordx4 %0, %3, off sc0 sc1\n\t"
                            "global_load_dwordx4 %1, %3, off offset:16 sc0 sc1\n\t"
                            "global_load_dwordx4 %2, %3, off offset:32 sc0 sc1\n\t"
                            "s_waitcnt vmcnt(0)"
                            : "=&v"(fr0), "=&v"(fr1), "=&v"(fr2)
                            : "v"(fp1) : "memory");
                        if (ALL12(fr0, fr1, fr2)) break;
                        __builtin_amdgcn_s_sleep(2);
                    }
                }
                Ymax = Y1;
            }
            xz_n  = __float_as_uint(out[(size_t)(t + 1) * BH_ + xoff]);
            xnn_n = xn[(size_t)(t + 1) * BH_ + xoff];
            // fire-and-forget flag loads for the NEXT pair (verified next step)
            const int Yf = (Y1 + 1 < 1024) ? Y1 + 1 : 1023;
            const unsigned int* fpn = xflag + (size_t)Yf * 12;
            asm volatile(
                "global_load_dwordx4 %0, %3, off sc0 sc1\n\t"
                "global_load_dwordx4 %1, %3, off offset:16 sc0 sc1\n\t"
                "global_load_dwordx4 %2, %3, off offset:32 sc0 sc1"
                : "=&v"(fr0), "=&v"(fr1), "=&v"(fr2) : "v"(fpn) : "memory");
        }
        BAR();

        // ---- matvec (48 MFMA) + gates ----
        fx4 ar = {0.f,0.f,0.f,0.f}, az = {0.f,0.f,0.f,0.f}, an = {0.f,0.f,0.f,0.f};
#pragma unroll
        for (int kc = 0; kc < 16; ++kc) {
            sx8 a = *(const sx8*)&hst[p1][(kc * 16 + (lane & 3) * 4 + (lane >> 4)) * 8];
            ar = __builtin_amdgcn_mfma_f32_16x16x32_bf16(a, wfr[kc], ar, 0, 0, 0);
            az = __builtin_amdgcn_mfma_f32_16x16x32_bf16(a, wfz[kc], az, 0, 0, 0);
            an = __builtin_amdgcn_mfma_f32_16x16x32_bf16(a, wfn[kc], an, 0, 0, 0);
        }
        const float sr = (r == 0) ? ar[0] : (r == 1) ? ar[1] : (r == 2) ? ar[2] : ar[3];
        const float sz = (r == 0) ? az[0] : (r == 1) ? az[1] : (r == 2) ? az[2] : az[3];
        const float sn = (r == 0) ? an[0] : (r == 1) ? an[1] : (r == 2) ? an[2] : an[3];
        const float arx = sr + bf2f((unsigned short)(xz_c & 0xffffu)) + bhr_v;
        const float azx = sz + bf2f((unsigned short)(xz_c >> 16)) + bhz_v;
        // fast sigmoid / tanh (R12-validated: absmax bit-identical)
        const float rg = __builtin_amdgcn_rcpf(1.f + __expf(-arx));
        const float zg = __builtin_amdgcn_rcpf(1.f + __expf(-azx));
        const float ti = bf2f(xnn_c) + rg * (sn + bhn_v);
        const float nn = 1.f - 2.f * __builtin_amdgcn_rcpf(__expf(2.f * ti) + 1.f);
        const float hv = (1.f - zg) * nn + zg * hprev;
        hprev = hv;

        // ---- publish own cols from registers (DPP quad pack) ----
        {
            const unsigned int hu1 = (unsigned int)__builtin_amdgcn_mov_dpp(
                (int)__float_as_uint(hv), 0xB1, 0xF, 0xF, true);
            const unsigned int pk01 = cvtpk(hv, __uint_as_float(hu1));
            const unsigned int pk23 = (unsigned int)__builtin_amdgcn_mov_dpp(
                (int)pk01, 0x4E, 0xF, 0xF, true);
            if ((lane & 3) == 0) {
                const int qg = wv * 4 + ((lane & 15) >> 2);
                const unsigned int tag = (unsigned int)t;
                ux4 pk4; pk4.x = tag; pk4.y = pk01; pk4.z = pk23; pk4.w = tag;
                char* addr = (char*)pkt +
                    ((((size_t)(p0 * 64 + 4 * g + r)) * NMEM + m) * 256
                     + (size_t)qg * 16);
                asm volatile("global_store_dwordx4 %0, %1, off sc0 sc1"
                             :: "v"(addr), "v"(pk4) : "memory");
            }
        }
        {
            const int unit = ((jcol >> 5) << 4) + r * 4 + ((jcol >> 3) & 3);
            hst[p0][unit * 8 + (jcol & 7)] = f2bf(hv);
        }
        out[(size_t)t * BH_ + xoff] = hv;
        if (t == S_ - 1) out[(size_t)S_ * BH_ + xoff] = hv;
        xz_c = xz_n; xnn_c = xnn_n;
    }
}

extern "C" void kernel_launch(void* const* d_in, const int* in_sizes, int n_in,
                              void* d_out, int out_size, void* d_ws, size_t ws_size,
                              hipStream_t stream) {
    (void)in_sizes; (void)n_in; (void)out_size; (void)ws_size;
    const float* x    = (const float*)d_in[0];
    const float* Wir  = (const float*)d_in[1];
    const float* bir  = (const float*)d_in[2];
    const float* Whr  = (const float*)d_in[3];
    const float* bhr  = (const float*)d_in[4];
    const float* Wiz  = (const float*)d_in[5];
    const float* biz  = (const float*)d_in[6];
    const float* Whz  = (const float*)d_in[7];
    const float* bhz  = (const float*)d_in[8];
    const float* Win  = (const float*)d_in[9];
    const float* bin_ = (const float*)d_in[10];
    const float* Whn  = (const float*)d_in[11];
    const float* bhn  = (const float*)d_in[12];

    unsigned short* xn = (unsigned short*)d_ws;                      // 128 MiB
    char* base = (char*)d_ws + (size_t)S_ * BH_ * 2;
    unsigned int* pkt   = (unsigned int*)base;                       // 256 KiB
    unsigned int* xflag = (unsigned int*)(base + 256 * 1024);        // 48 KiB

    // Clear the launch-local handshake flags EVERY call (replay-safe).
    hipMemsetAsync(xflag, 0, 12 * 1024 * sizeof(unsigned int), stream);

    fused_k<<<dim3(NGRU + 12 * 1024, 1, 1), 256, 0, stream>>>(
        x, Wir, bir, Wiz, biz, Win, bin_,
        Whr, bhr, Whz, bhz, Whn, bhn,
        (float*)d_out, xn, pkt, xflag);
}